// Round 9
// baseline (32.619 us; speedup 1.0000x reference)
//
#include <hip/hip_runtime.h>

#define NB 1024
#define ND 256
#define APB 8              // anchors per block (4 per wave-pair)
#define JCH 256            // j's per block
#define NTHR 256           // 4 waves
#define MARGINF 0.3f
#define BIGV 1e9f
#define D2R 0.017453292519943295f
#define HD2R 0.008726646259971648f

// haversine 'a' thresholds: sin^2(T/(2*6371000)) (validated rounds 1-8)
#define A_POS 3.8495040e-12f   // 25 m
#define A_NEG 6.1592064e-11f   // 100 m

__device__ __forceinline__ float d4(float4 a, float4 b, float acc) {
    return fmaf(a.x,b.x, fmaf(a.y,b.y, fmaf(a.z,b.z, fmaf(a.w,b.w, acc))));
}

// Splitting butterfly over an 8-lane group: 4 values -> each lane holds the
// FULL 8-lane sum of value a_local(lane) = 2*(lane&1) + ((lane>>1)&1).
// 3 shuffles, depth 3. (Pattern validated via reduce8 in round 8.)
__device__ __forceinline__ float reduce4(const float v[4], int lane) {
    const bool b0 = lane & 1, b1 = lane & 2;
    float n1[2];
    #pragma unroll
    for (int i = 0; i < 2; ++i) {
        float sv = b0 ? v[i]   : v[2+i];
        float kp = b0 ? v[2+i] : v[i];
        n1[i] = kp + __shfl_xor(sv, 1);
    }
    float sv = b1 ? n1[0] : n1[1];
    float kp = b1 ? n1[1] : n1[0];
    float n2 = kp + __shfl_xor(sv, 2);
    return n2 + __shfl_xor(n2, 4);
}

// K0: per-point prep {sqnorm, lat_deg, lon_deg, cos(lat)} (proven round 7)
__global__ __launch_bounds__(256) void prep_kernel(
    const float* __restrict__ emb, const float* __restrict__ gps,
    float4* __restrict__ prep)
{
    const int tid = threadIdx.x;
    const int row = blockIdx.x*16 + (tid >> 4);
    const int kk  = tid & 15;
    const float4* r4 = (const float4*)emb + (size_t)row*64;
    float s = 0.f;
    #pragma unroll
    for (int c = 0; c < 4; ++c) { float4 v = r4[kk + 16*c]; s = d4(v, v, s); }
    #pragma unroll
    for (int off = 1; off < 16; off <<= 1) s += __shfl_xor(s, off);
    if (kk == 0) {
        float2 g = ((const float2*)gps)[row];
        prep[row] = make_float4(s, g.x, g.y, cosf(g.x * D2R));
    }
}

// K1: no-LDS gram. Block = 8 anchors x 256 j. Waves 0,1 own anchors 0-3,
// waves 2,3 own anchors 4-7. Lane: jj=lane>>3 (8 rows/wave/iter), kk=lane&7
// (8-way k-split, 32 floats). 3 shuffles per iter (reduce4).
__global__ __launch_bounds__(NTHR, 2) void gram_kernel(
    const float* __restrict__ emb, const float4* __restrict__ prep,
    float* __restrict__ sEnc, float* __restrict__ pP)
{
    __shared__ float sPm[4][APB];

    const int tid  = threadIdx.x;
    const int lane = tid & 63;
    const int w    = tid >> 6;
    const int jj   = lane >> 3;          // 0..7
    const int kk   = lane & 7;           // k-slice
    const int ah   = (w >> 1) * 4;       // wave's anchor base (0 or 4)
    const int a    = ah + 2*(lane & 1) + ((lane >> 1) & 1);   // lane's anchor
    const int ig   = blockIdx.x >> 2;
    const int c    = blockIdx.x & 3;
    const int i0   = ig * APB;
    const int jbase = c * JCH;
    const float4* __restrict__ emb4 = (const float4*)emb;

    // wave's 4 anchors, 32-float slices: 32 float4 = 128 VGPR
    float4 cA[4][8];
    #pragma unroll
    for (int ai = 0; ai < 4; ++ai)
        #pragma unroll
        for (int q = 0; q < 8; ++q)
            cA[ai][q] = emb4[(size_t)(i0+ah+ai)*64 + kk + 8*q];

    // this lane's anchor prep data
    const float4 pa = prep[i0 + a];
    const float SA = pa.x, latA = pa.y, lonA = pa.z, cosA = pa.w;

    float pmax = -1.f;

    // software-pipelined j loop: 16 iters x 8 rows/wave (waves 0,2: rows 0-7; 1,3: 8-15)
    int jr = jbase + (w & 1)*8 + jj;
    float4 v[8];
    #pragma unroll
    for (int q = 0; q < 8; ++q) v[q] = emb4[(size_t)jr*64 + kk + 8*q];
    float4 pv = prep[jr];

    #pragma unroll 2
    for (int t = 0; t < 16; ++t) {
        float4 wv[8]; float4 pw;
        int jr2 = jbase + (t+1)*16 + (w & 1)*8 + jj;
        if (t < 15) {
            #pragma unroll
            for (int q = 0; q < 8; ++q) wv[q] = emb4[(size_t)jr2*64 + kk + 8*q];
            pw = prep[jr2];
        }
        // 4 anchor dots over this lane's 32-float slice
        float ac[4];
        #pragma unroll
        for (int ai = 0; ai < 4; ++ai) {
            float s = 0.f;
            #pragma unroll
            for (int q = 0; q < 8; ++q) s = d4(v[q], cA[ai][q], s);
            ac[ai] = s;
        }
        const float dot = reduce4(ac, lane);      // 3 DS ops, depth 3

        float d2v = SA + pv.x - 2.f*dot;
        d2v = d2v > 0.f ? d2v : 0.f;

        const float sla = sinf((pv.y - latA) * HD2R);
        const float slo = sinf((pv.z - lonA) * HD2R);
        const float hav = fmaf(sla, sla, (cosA * pv.w) * (slo*slo));
        const bool pos = (hav < A_POS) && (jr != i0 + a);
        const bool neg = (hav > A_NEG);

        pmax = fmaxf(pmax, pos ? d2v : -1.f);
        if (!(lane & 4))                          // one writer per (a, j)
            sEnc[(size_t)(i0+a)*NB + jr] = neg ? d2v : BIGV;

        jr = jr2; pv = pw;
        #pragma unroll
        for (int q = 0; q < 8; ++q) v[q] = wv[q];
    }

    // pmax: reduce over lanes sharing the same anchor (bits 2..5)
    #pragma unroll
    for (int off = 4; off < 64; off <<= 1) pmax = fmaxf(pmax, __shfl_xor(pmax, off));
    if (lane < 4) sPm[w][a] = pmax;               // a covers ah..ah+3 over lanes 0..3
    __syncthreads();
    if (tid < 8) {
        const int w0 = (tid < 4) ? 0 : 2;         // wave pair covering this anchor
        pP[(i0 + tid)*4 + c] = fmaxf(sPm[w0][tid], sPm[w0+1][tid]);
    }
}

// K2: per-row finalize (proven round 8)
__global__ __launch_bounds__(256) void rows_kernel(
    const float* __restrict__ sEnc, const float* __restrict__ pP,
    float* __restrict__ tri, float* __restrict__ val)
{
    const int tid = threadIdx.x, lane = tid & 63, w = tid >> 6;
    const int i = blockIdx.x*4 + w;

    const float dap2 = fmaxf(fmaxf(pP[i*4+0], pP[i*4+1]), fmaxf(pP[i*4+2], pP[i*4+3]));
    const bool has_pos = dap2 > -0.5f;
    float lo2 = -1.f, hi2 = -1.f;
    if (has_pos) { const float hb = sqrtf(dap2) + MARGINF; lo2 = dap2; hi2 = hb*hb; }

    float nmin = BIGV, smin = BIGV;
    const float4* __restrict__ row = (const float4*)sEnc + (size_t)i*256;
    #pragma unroll
    for (int p = 0; p < 4; ++p) {
        const float4 x = row[p*64 + lane];
        #pragma unroll
        for (int q = 0; q < 4; ++q) {
            const float xc = (q==0) ? x.x : (q==1) ? x.y : (q==2) ? x.z : x.w;
            nmin = fminf(nmin, xc);
            smin = fminf(smin, (xc > lo2 && xc < hi2) ? xc : BIGV);
        }
    }
    #pragma unroll
    for (int off = 1; off < 64; off <<= 1) {
        nmin = fminf(nmin, __shfl_xor(nmin, off));
        smin = fminf(smin, __shfl_xor(smin, off));
    }
    if (lane == 0) {
        const bool has_neg  = nmin < 0.5f*BIGV;
        const bool has_semi = smin < 0.5f*BIGV;
        const float dan2 = has_semi ? smin : nmin;
        const float dap  = has_pos ? sqrtf(dap2) : 0.f;
        float t = dap - sqrtf(dan2) + MARGINF;
        t = t > 0.f ? t : 0.f;
        const bool valid = has_pos && has_neg;
        tri[i] = valid ? t : 0.f;
        val[i] = valid ? 1.f : 0.f;
    }
}

__global__ __launch_bounds__(256) void finalize_kernel(
    const float* __restrict__ tri, const float* __restrict__ val, float* __restrict__ out)
{
    const int tid = threadIdx.x;
    float st = 0.f, sv = 0.f;
    #pragma unroll
    for (int g = 0; g < 4; ++g) { st += tri[tid + (g<<8)]; sv += val[tid + (g<<8)]; }
    #pragma unroll
    for (int off = 1; off < 64; off <<= 1) { st += __shfl_xor(st, off); sv += __shfl_xor(sv, off); }
    __shared__ float rt[4], rv[4];
    if ((tid & 63) == 0) { rt[tid>>6] = st; rv[tid>>6] = sv; }
    __syncthreads();
    if (tid == 0) {
        float t = rt[0]+rt[1]+rt[2]+rt[3];
        float v = rv[0]+rv[1]+rv[2]+rv[3];
        out[0] = t / fmaxf(v, 1.f);
    }
}

extern "C" void kernel_launch(void* const* d_in, const int* in_sizes, int n_in,
                              void* d_out, int out_size, void* d_ws, size_t ws_size,
                              hipStream_t stream) {
    const float* emb = (const float*)d_in[0];   // [1024,256] f32
    const float* gps = (const float*)d_in[1];   // [1024,2]  f32
    float* ws = (float*)d_ws;

    float*  sEnc = ws;                    // [1024*1024]  4 MB
    float4* prep = (float4*)(ws + 1048576);     // [1024] float4
    float*  pP   = ws + 1048576 + 4096;   // [1024*4]
    float*  tri  = pP + 4096;             // [1024]
    float*  val  = tri + 1024;            // [1024]

    prep_kernel<<<64, 256, 0, stream>>>(emb, gps, prep);
    gram_kernel<<<512, NTHR, 0, stream>>>(emb, prep, sEnc, pP);
    rows_kernel<<<256, 256, 0, stream>>>(sEnc, pP, tri, val);
    finalize_kernel<<<1, 256, 0, stream>>>(tri, val, (float*)d_out);
}

// Round 10
// 28.577 us; speedup vs baseline: 1.1414x; 1.1414x over previous
//
#include <hip/hip_runtime.h>
#include <hip/hip_bf16.h>

typedef __attribute__((ext_vector_type(8))) short bf16x8;
typedef __attribute__((ext_vector_type(4))) float f32x4;

#define NB 1024
#define ND 256
#define KC 512             // C = [H | L] columns
#define MARGINF 0.3f
#define BIGV 1e9f
#define D2R 0.017453292519943295f
#define HD2R 0.008726646259971648f

// haversine 'a' thresholds: sin^2(T/(2*6371000)) (validated rounds 1-9)
#define A_POS 3.8495040e-12f   // 25 m
#define A_NEG 6.1592064e-11f   // 100 m

__device__ __forceinline__ float d4(float4 a, float4 b, float acc) {
    return fmaf(a.x,b.x, fmaf(a.y,b.y, fmaf(a.z,b.z, fmaf(a.w,b.w, acc))));
}

// K0: per-point prep {sqnorm(exact f32), lat, lon, cos(lat)} + build C=[H|L] bf16
__global__ __launch_bounds__(256) void prep_kernel(
    const float* __restrict__ emb, const float* __restrict__ gps,
    float4* __restrict__ prep, unsigned short* __restrict__ C)
{
    const int tid = threadIdx.x;
    const int row = blockIdx.x*16 + (tid >> 4);
    const int kk  = tid & 15;
    const float4* r4 = (const float4*)emb + (size_t)row*64;
    float s = 0.f;
    #pragma unroll
    for (int c = 0; c < 4; ++c) {
        float4 v = r4[kk + 16*c];
        s = d4(v, v, s);
        float fv[4] = {v.x, v.y, v.z, v.w};
        unsigned short hh[4], ll[4];
        #pragma unroll
        for (int q = 0; q < 4; ++q) {
            __hip_bfloat16 hb = __float2bfloat16(fv[q]);
            float hf = __bfloat162float(hb);
            __hip_bfloat16 lb = __float2bfloat16(fv[q] - hf);
            hh[q] = *(unsigned short*)&hb;
            ll[q] = *(unsigned short*)&lb;
        }
        *(ushort4*)(C + (size_t)row*KC +       4*(kk+16*c)) = make_ushort4(hh[0],hh[1],hh[2],hh[3]);
        *(ushort4*)(C + (size_t)row*KC + 256 + 4*(kk+16*c)) = make_ushort4(ll[0],ll[1],ll[2],ll[3]);
    }
    #pragma unroll
    for (int off = 1; off < 16; off <<= 1) s += __shfl_xor(s, off);
    if (kk == 0) {
        float2 g = ((const float2*)gps)[row];
        prep[row] = make_float4(s, g.x, g.y, cosf(g.x * D2R));
    }
}

// K1: MFMA Gram. 64x64 tile per block (256 thr, 4 waves of 32x32).
// G = C*C^T via mfma_f32_16x16x32_bf16; d^2 = sq_i + sq_j - 2G.
// A/B frags: lane holds 8 contiguous bf16 at row (lane&15), k-block (lane>>4).
// C/D frags: col = lane&15, row = (lane>>4)*4 + reg  [guide, m89-verified].
__global__ __launch_bounds__(256) void gram_mfma(
    const unsigned short* __restrict__ C, const float4* __restrict__ prep,
    float* __restrict__ sEnc, float* __restrict__ pP)
{
    __shared__ float sRed[64][33];   // [row-local][16 cols x 2 wave-cols], +1 pad

    const int tid = threadIdx.x, lane = tid & 63, w = tid >> 6;
    const int wr = w >> 1, wc = w & 1;              // wave tile (32x32) coords
    const int ib = blockIdx.x & 15, jb = blockIdx.x >> 4;
    const int i0 = ib*64, j0 = jb*64;
    const int lr = lane & 15, lk = lane >> 4;       // frag row/col, k-block
    const short* Cs = (const short*)C;

    f32x4 acc[2][2] = {};
    #pragma unroll 4
    for (int ks = 0; ks < 16; ++ks) {
        bf16x8 a0 = *(const bf16x8*)(Cs + (size_t)(i0 + wr*32      + lr)*KC + ks*32 + lk*8);
        bf16x8 a1 = *(const bf16x8*)(Cs + (size_t)(i0 + wr*32 + 16 + lr)*KC + ks*32 + lk*8);
        bf16x8 b0 = *(const bf16x8*)(Cs + (size_t)(j0 + wc*32      + lr)*KC + ks*32 + lk*8);
        bf16x8 b1 = *(const bf16x8*)(Cs + (size_t)(j0 + wc*32 + 16 + lr)*KC + ks*32 + lk*8);
        acc[0][0] = __builtin_amdgcn_mfma_f32_16x16x32_bf16(a0, b0, acc[0][0], 0, 0, 0);
        acc[0][1] = __builtin_amdgcn_mfma_f32_16x16x32_bf16(a0, b1, acc[0][1], 0, 0, 0);
        acc[1][0] = __builtin_amdgcn_mfma_f32_16x16x32_bf16(a1, b0, acc[1][0], 0, 0, 0);
        acc[1][1] = __builtin_amdgcn_mfma_f32_16x16x32_bf16(a1, b1, acc[1][1], 0, 0, 0);
    }

    // epilogue: d^2, haversine masks, sEnc encode, per-row pmax partials
    float4 pj[2];
    pj[0] = prep[j0 + wc*32 + lr];
    pj[1] = prep[j0 + wc*32 + 16 + lr];

    #pragma unroll
    for (int fi = 0; fi < 2; ++fi) {
        #pragma unroll
        for (int r = 0; r < 4; ++r) {
            const int rl = wr*32 + fi*16 + lk*4 + r;    // row-local 0..63
            const int gi = i0 + rl;
            const float4 pi = prep[gi];
            float pmax = -1.f;
            #pragma unroll
            for (int fj = 0; fj < 2; ++fj) {
                const int gj = j0 + wc*32 + fj*16 + lr;
                float d2v = pi.x + pj[fj].x - 2.f*acc[fi][fj][r];
                d2v = d2v > 0.f ? d2v : 0.f;
                const float sla = sinf((pj[fj].y - pi.y) * HD2R);
                const float slo = sinf((pj[fj].z - pi.z) * HD2R);
                const float hav = fmaf(sla, sla, (pi.w * pj[fj].w) * (slo*slo));
                const bool pos = (hav < A_POS) && (gi != gj);
                const bool neg = (hav > A_NEG);
                pmax = fmaxf(pmax, pos ? d2v : -1.f);
                sEnc[(size_t)gi*NB + gj] = neg ? d2v : BIGV;
            }
            sRed[rl][lr + 16*wc] = pmax;
        }
    }
    __syncthreads();
    if (tid < 64) {
        float m = sRed[tid][0];
        #pragma unroll
        for (int c = 1; c < 32; ++c) m = fmaxf(m, sRed[tid][c]);
        pP[(i0 + tid)*16 + jb] = m;     // unique (row, j-chunk) owner: plain store
    }
}

// K2: per-row finalize (r8-proven, pP widened to 16 chunks)
__global__ __launch_bounds__(256) void rows_kernel(
    const float* __restrict__ sEnc, const float* __restrict__ pP,
    float* __restrict__ tri, float* __restrict__ val)
{
    const int tid = threadIdx.x, lane = tid & 63, w = tid >> 6;
    const int i = blockIdx.x*4 + w;

    float p = pP[i*16 + (lane & 15)];
    #pragma unroll
    for (int off = 1; off < 16; off <<= 1) p = fmaxf(p, __shfl_xor(p, off));
    const float dap2 = p;
    const bool has_pos = dap2 > -0.5f;
    float lo2 = -1.f, hi2 = -1.f;
    if (has_pos) { const float hb = sqrtf(dap2) + MARGINF; lo2 = dap2; hi2 = hb*hb; }

    float nmin = BIGV, smin = BIGV;
    const float4* __restrict__ row = (const float4*)sEnc + (size_t)i*256;
    #pragma unroll
    for (int pss = 0; pss < 4; ++pss) {
        const float4 x = row[pss*64 + lane];
        #pragma unroll
        for (int q = 0; q < 4; ++q) {
            const float xc = (q==0) ? x.x : (q==1) ? x.y : (q==2) ? x.z : x.w;
            nmin = fminf(nmin, xc);
            smin = fminf(smin, (xc > lo2 && xc < hi2) ? xc : BIGV);
        }
    }
    #pragma unroll
    for (int off = 1; off < 64; off <<= 1) {
        nmin = fminf(nmin, __shfl_xor(nmin, off));
        smin = fminf(smin, __shfl_xor(smin, off));
    }
    if (lane == 0) {
        const bool has_neg  = nmin < 0.5f*BIGV;
        const bool has_semi = smin < 0.5f*BIGV;
        const float dan2 = has_semi ? smin : nmin;
        const float dap  = has_pos ? sqrtf(dap2) : 0.f;
        float t = dap - sqrtf(dan2) + MARGINF;
        t = t > 0.f ? t : 0.f;
        const bool valid = has_pos && has_neg;
        tri[i] = valid ? t : 0.f;
        val[i] = valid ? 1.f : 0.f;
    }
}

__global__ __launch_bounds__(256) void finalize_kernel(
    const float* __restrict__ tri, const float* __restrict__ val, float* __restrict__ out)
{
    const int tid = threadIdx.x;
    float st = 0.f, sv = 0.f;
    #pragma unroll
    for (int g = 0; g < 4; ++g) { st += tri[tid + (g<<8)]; sv += val[tid + (g<<8)]; }
    #pragma unroll
    for (int off = 1; off < 64; off <<= 1) { st += __shfl_xor(st, off); sv += __shfl_xor(sv, off); }
    __shared__ float rt[4], rv[4];
    if ((tid & 63) == 0) { rt[tid>>6] = st; rv[tid>>6] = sv; }
    __syncthreads();
    if (tid == 0) {
        float t = rt[0]+rt[1]+rt[2]+rt[3];
        float v = rv[0]+rv[1]+rv[2]+rv[3];
        out[0] = t / fmaxf(v, 1.f);
    }
}

extern "C" void kernel_launch(void* const* d_in, const int* in_sizes, int n_in,
                              void* d_out, int out_size, void* d_ws, size_t ws_size,
                              hipStream_t stream) {
    const float* emb = (const float*)d_in[0];   // [1024,256] f32
    const float* gps = (const float*)d_in[1];   // [1024,2]  f32
    float* ws = (float*)d_ws;

    float*          sEnc = ws;                          // 1024*1024 f32 = 4 MB
    unsigned short* Cbf  = (unsigned short*)(ws + 1048576);  // 1024*512 bf16 = 1 MB
    float4*         prep = (float4*)(ws + 1048576 + 262144); // 1024 float4
    float*          pP   = ws + 1048576 + 262144 + 4096;     // 1024*16
    float*          tri  = pP + 16384;                       // 1024
    float*          val  = tri + 1024;                       // 1024

    prep_kernel<<<64, 256, 0, stream>>>(emb, gps, prep, Cbf);
    gram_mfma<<<256, 256, 0, stream>>>(Cbf, prep, sEnc, pP);
    rows_kernel<<<256, 256, 0, stream>>>(sEnc, pP, tri, val);
    finalize_kernel<<<1, 256, 0, stream>>>(tri, val, (float*)d_out);
}

// Round 11
// 27.419 us; speedup vs baseline: 1.1896x; 1.0422x over previous
//
#include <hip/hip_runtime.h>
#include <hip/hip_bf16.h>

typedef __attribute__((ext_vector_type(8))) short bf16x8;
typedef __attribute__((ext_vector_type(4))) float f32x4;

#define NB 1024
#define ND 256
#define MARGINF 0.3f
#define BIGV 1e9f
#define D2R 0.017453292519943295f
#define HD2R 0.008726646259971648f

// haversine 'a' thresholds: sin^2(T/(2*6371000)) (validated rounds 1-10)
#define A_POS 3.8495040e-12f   // 25 m
#define A_NEG 6.1592064e-11f   // 100 m

__device__ __forceinline__ float d4(float4 a, float4 b, float acc) {
    return fmaf(a.x,b.x, fmaf(a.y,b.y, fmaf(a.z,b.z, fmaf(a.w,b.w, acc))));
}

// split 8 floats into bf16 hi (RNE) + bf16 of residual
__device__ __forceinline__ void splitHL(float4 v0, float4 v1, bf16x8& H, bf16x8& L) {
    float f[8] = {v0.x, v0.y, v0.z, v0.w, v1.x, v1.y, v1.z, v1.w};
    #pragma unroll
    for (int q = 0; q < 8; ++q) {
        __hip_bfloat16 h = __float2bfloat16(f[q]);
        float hf = __bfloat162float(h);
        __hip_bfloat16 l = __float2bfloat16(f[q] - hf);
        H[q] = *(short*)&h;
        L[q] = *(short*)&l;
    }
}

// K1: self-contained MFMA Gram, 64x64 tile per block (256 thr, 4 waves of 32x32).
// In-register H/L split; G = HH' + LH' + HL' (LL' ~2^-18 dropped).
// d^2 = sq_i + sq_j - 2G with exact fp32 norms from the LDS prologue.
// A/B frags: lane holds 8 contiguous elems at row (lane&15), k-block (lane>>4).
// C/D frags: col = lane&15, row = (lane>>4)*4 + reg  [validated round 10].
__global__ __launch_bounds__(256) void gram_mfma(
    const float* __restrict__ emb, const float* __restrict__ gps,
    float* __restrict__ sEnc, float* __restrict__ pP)
{
    __shared__ float  sSqI[64], sSqJ[64];
    __shared__ float4 sGI[64], sGJ[64];    // {lat, lon, cos, _}
    __shared__ float  sRed[64][33];

    const int tid = threadIdx.x, lane = tid & 63, w = tid >> 6;
    const int wr = w >> 1, wc = w & 1;
    const int ib = blockIdx.x & 15, jb = blockIdx.x >> 4;
    const int i0 = ib*64, j0 = jb*64;
    const int lr = lane & 15, lk = lane >> 4;
    const float4* __restrict__ emb4 = (const float4*)emb;

    // ---- prologue: row norms (exact fp32) + gps scalars for both panels ----
    {
        const int half = tid & 1, r = (tid >> 1) & 63;
        const int base = (tid < 128) ? i0 : j0;
        const float4* rp = emb4 + (size_t)(base + r)*64 + half*32;
        float s = 0.f;
        #pragma unroll
        for (int q = 0; q < 32; ++q) s = d4(rp[q], rp[q], s);
        s += __shfl_xor(s, 1);
        if (half == 0) { if (tid < 128) sSqI[r] = s; else sSqJ[r] = s; }
    }
    if (tid < 128) {
        const int r = tid & 63;
        const int base = (tid < 64) ? i0 : j0;
        float2 g = ((const float2*)gps)[base + r];
        float4 gi = make_float4(g.x, g.y, cosf(g.x * D2R), 0.f);
        if (tid < 64) sGI[r] = gi; else sGJ[r] = gi;
    }
    __syncthreads();

    // ---- MFMA loop: 8 k-windows x {8 loads -> 8 frags -> 12 MFMAs} ----
    f32x4 acc[2][2] = {};
    #pragma unroll 2
    for (int k8 = 0; k8 < 8; ++k8) {
        const int co = k8*8 + lk*2;   // float4 col index within the 64-float4 row
        const float4* pa0 = emb4 + (size_t)(i0 + wr*32      + lr)*64 + co;
        const float4* pa1 = emb4 + (size_t)(i0 + wr*32 + 16 + lr)*64 + co;
        const float4* pb0 = emb4 + (size_t)(j0 + wc*32      + lr)*64 + co;
        const float4* pb1 = emb4 + (size_t)(j0 + wc*32 + 16 + lr)*64 + co;
        bf16x8 a0H,a0L,a1H,a1L,b0H,b0L,b1H,b1L;
        splitHL(pa0[0], pa0[1], a0H, a0L);
        splitHL(pa1[0], pa1[1], a1H, a1L);
        splitHL(pb0[0], pb0[1], b0H, b0L);
        splitHL(pb1[0], pb1[1], b1H, b1L);
        acc[0][0] = __builtin_amdgcn_mfma_f32_16x16x32_bf16(a0H, b0H, acc[0][0], 0,0,0);
        acc[0][1] = __builtin_amdgcn_mfma_f32_16x16x32_bf16(a0H, b1H, acc[0][1], 0,0,0);
        acc[1][0] = __builtin_amdgcn_mfma_f32_16x16x32_bf16(a1H, b0H, acc[1][0], 0,0,0);
        acc[1][1] = __builtin_amdgcn_mfma_f32_16x16x32_bf16(a1H, b1H, acc[1][1], 0,0,0);
        acc[0][0] = __builtin_amdgcn_mfma_f32_16x16x32_bf16(a0L, b0H, acc[0][0], 0,0,0);
        acc[0][1] = __builtin_amdgcn_mfma_f32_16x16x32_bf16(a0L, b1H, acc[0][1], 0,0,0);
        acc[1][0] = __builtin_amdgcn_mfma_f32_16x16x32_bf16(a1L, b0H, acc[1][0], 0,0,0);
        acc[1][1] = __builtin_amdgcn_mfma_f32_16x16x32_bf16(a1L, b1H, acc[1][1], 0,0,0);
        acc[0][0] = __builtin_amdgcn_mfma_f32_16x16x32_bf16(a0H, b0L, acc[0][0], 0,0,0);
        acc[0][1] = __builtin_amdgcn_mfma_f32_16x16x32_bf16(a0H, b1L, acc[0][1], 0,0,0);
        acc[1][0] = __builtin_amdgcn_mfma_f32_16x16x32_bf16(a1H, b0L, acc[1][0], 0,0,0);
        acc[1][1] = __builtin_amdgcn_mfma_f32_16x16x32_bf16(a1H, b1L, acc[1][1], 0,0,0);
    }

    // ---- epilogue: d^2, haversine masks, sEnc encode, per-row pmax partials ----
    float sqj[2]; float4 gj2[2];
    sqj[0] = sSqJ[wc*32 + lr];      gj2[0] = sGJ[wc*32 + lr];
    sqj[1] = sSqJ[wc*32 + 16 + lr]; gj2[1] = sGJ[wc*32 + 16 + lr];

    #pragma unroll
    for (int fi = 0; fi < 2; ++fi) {
        #pragma unroll
        for (int r = 0; r < 4; ++r) {
            const int rl = wr*32 + fi*16 + lk*4 + r;
            const int gi = i0 + rl;
            const float sqi = sSqI[rl];
            const float4 gvi = sGI[rl];
            float pmax = -1.f;
            #pragma unroll
            for (int fj = 0; fj < 2; ++fj) {
                const int gj = j0 + wc*32 + fj*16 + lr;
                float d2v = sqi + sqj[fj] - 2.f*acc[fi][fj][r];
                d2v = d2v > 0.f ? d2v : 0.f;
                const float sla = sinf((gj2[fj].x - gvi.x) * HD2R);
                const float slo = sinf((gj2[fj].y - gvi.y) * HD2R);
                const float hav = fmaf(sla, sla, (gvi.z * gj2[fj].z) * (slo*slo));
                const bool pos = (hav < A_POS) && (gi != gj);
                const bool neg = (hav > A_NEG);
                pmax = fmaxf(pmax, pos ? d2v : -1.f);
                sEnc[(size_t)gi*NB + gj] = neg ? d2v : BIGV;
            }
            sRed[rl][lr + 16*wc] = pmax;
        }
    }
    __syncthreads();
    if (tid < 64) {
        float m = sRed[tid][0];
        #pragma unroll
        for (int c = 1; c < 32; ++c) m = fmaxf(m, sRed[tid][c]);
        pP[(i0 + tid)*16 + jb] = m;
    }
}

// K2: per-row finalize (proven rounds 8-10)
__global__ __launch_bounds__(256) void rows_kernel(
    const float* __restrict__ sEnc, const float* __restrict__ pP,
    float* __restrict__ tri, float* __restrict__ val)
{
    const int tid = threadIdx.x, lane = tid & 63, w = tid >> 6;
    const int i = blockIdx.x*4 + w;

    float p = pP[i*16 + (lane & 15)];
    #pragma unroll
    for (int off = 1; off < 16; off <<= 1) p = fmaxf(p, __shfl_xor(p, off));
    const float dap2 = p;
    const bool has_pos = dap2 > -0.5f;
    float lo2 = -1.f, hi2 = -1.f;
    if (has_pos) { const float hb = sqrtf(dap2) + MARGINF; lo2 = dap2; hi2 = hb*hb; }

    float nmin = BIGV, smin = BIGV;
    const float4* __restrict__ row = (const float4*)sEnc + (size_t)i*256;
    #pragma unroll
    for (int pss = 0; pss < 4; ++pss) {
        const float4 x = row[pss*64 + lane];
        #pragma unroll
        for (int q = 0; q < 4; ++q) {
            const float xc = (q==0) ? x.x : (q==1) ? x.y : (q==2) ? x.z : x.w;
            nmin = fminf(nmin, xc);
            smin = fminf(smin, (xc > lo2 && xc < hi2) ? xc : BIGV);
        }
    }
    #pragma unroll
    for (int off = 1; off < 64; off <<= 1) {
        nmin = fminf(nmin, __shfl_xor(nmin, off));
        smin = fminf(smin, __shfl_xor(smin, off));
    }
    if (lane == 0) {
        const bool has_neg  = nmin < 0.5f*BIGV;
        const bool has_semi = smin < 0.5f*BIGV;
        const float dan2 = has_semi ? smin : nmin;
        const float dap  = has_pos ? sqrtf(dap2) : 0.f;
        float t = dap - sqrtf(dan2) + MARGINF;
        t = t > 0.f ? t : 0.f;
        const bool valid = has_pos && has_neg;
        tri[i] = valid ? t : 0.f;
        val[i] = valid ? 1.f : 0.f;
    }
}

__global__ __launch_bounds__(256) void finalize_kernel(
    const float* __restrict__ tri, const float* __restrict__ val, float* __restrict__ out)
{
    const int tid = threadIdx.x;
    float st = 0.f, sv = 0.f;
    #pragma unroll
    for (int g = 0; g < 4; ++g) { st += tri[tid + (g<<8)]; sv += val[tid + (g<<8)]; }
    #pragma unroll
    for (int off = 1; off < 64; off <<= 1) { st += __shfl_xor(st, off); sv += __shfl_xor(sv, off); }
    __shared__ float rt[4], rv[4];
    if ((tid & 63) == 0) { rt[tid>>6] = st; rv[tid>>6] = sv; }
    __syncthreads();
    if (tid == 0) {
        float t = rt[0]+rt[1]+rt[2]+rt[3];
        float v = rv[0]+rv[1]+rv[2]+rv[3];
        out[0] = t / fmaxf(v, 1.f);
    }
}

extern "C" void kernel_launch(void* const* d_in, const int* in_sizes, int n_in,
                              void* d_out, int out_size, void* d_ws, size_t ws_size,
                              hipStream_t stream) {
    const float* emb = (const float*)d_in[0];   // [1024,256] f32
    const float* gps = (const float*)d_in[1];   // [1024,2]  f32
    float* ws = (float*)d_ws;

    float* sEnc = ws;                    // 1024*1024 f32 = 4 MB
    float* pP   = ws + 1048576;          // 1024*16
    float* tri  = pP + 16384;            // 1024
    float* val  = tri + 1024;            // 1024

    gram_mfma<<<256, 256, 0, stream>>>(emb, gps, sEnc, pP);
    rows_kernel<<<256, 256, 0, stream>>>(sEnc, pP, tri, val);
    finalize_kernel<<<1, 256, 0, stream>>>(tri, val, (float*)d_out);
}